// Round 5
// baseline (38.063 us; speedup 1.0000x reference)
//
#include <hip/hip_runtime.h>
#include <math.h>

#define BB 4
#define NN 1024
#define MM 1024
#define HH 64
#define NT 8              // n-tiles
#define BN 128            // n per block
#define BM 128            // m per block
#define MT (MM / BM)      // 8 m-tiles

static constexpr float NEG_BIG = -3.0e38f;
static constexpr float SCALE = -0.72134752044448170f;   // -0.5 * log2(e)

// ---------------- Kernel 1: fused prep (K-MLP, Q-MLP, vhat = V.Wo) ----------------
// grid 144 x 256.
//   bx in [0,128): MLP blocks. type=bx>>6, rowgrp=(bx&63)>>3, chunk=bx&7.
//     Thread: 2 rows (rowgrp*512+tid, +256), 8 outputs (chunk*8..+7).
//     Weights staged in LDS once; inner loop = 3 uniform ds_read_b128 + 24 VALU per hi.
//   bx in [128,144): vhat blocks, vhat[row] = relu(x@Wv1+bv1)@(Wv2@Wo) + bv2.Wo.
__global__ __launch_bounds__(256)
void prep_kernel(const float* __restrict__ coords_f,
                 const float* __restrict__ values_f,
                 const float* __restrict__ coords_t,
                 const float* __restrict__ Wk1, const float* __restrict__ bk1,
                 const float* __restrict__ Wk2, const float* __restrict__ bk2,
                 const float* __restrict__ Wq1, const float* __restrict__ bq1,
                 const float* __restrict__ Wq2, const float* __restrict__ bq2,
                 const float* __restrict__ Wv1, const float* __restrict__ bv1,
                 const float* __restrict__ Wv2, const float* __restrict__ bv2,
                 const float* __restrict__ Wo,
                 float* __restrict__ Kout, float* __restrict__ Qout,
                 float* __restrict__ vhat) {
    const int bx = blockIdx.x;
    const int tid = threadIdx.x;

    if (bx < 128) {
        const int type   = bx >> 6;           // 0 = K, 1 = Q
        const int sub    = bx & 63;
        const int rowgrp = sub >> 3;          // 0..7 (512 rows each)
        const int chunk  = sub & 7;
        const int co     = chunk * 8;

        const float* in = type ? coords_t : coords_f;
        const float* W1 = type ? Wq1 : Wk1;
        const float* b1 = type ? bq1 : bk1;
        const float* W2 = type ? Wq2 : Wk2;
        const float* b2 = type ? bq2 : bk2;
        float* out = type ? Qout : Kout;

        __shared__ float4 hrow[64];     // {W1[0][hi], W1[1][hi], W1[2][hi], b1[hi]}
        __shared__ float4 w2s[128];     // [hi][2] : W2[hi, co..co+7]
        if (tid < 64) {
            hrow[tid] = make_float4(W1[tid], W1[64 + tid], W1[128 + tid], b1[tid]);
        } else if (tid < 192) {
            const int t = tid - 64;     // 0..127
            const int hi = t >> 1, half = t & 1;
            w2s[t] = *reinterpret_cast<const float4*>(W2 + hi * 64 + co + half * 4);
        }
        __syncthreads();

        const int r0 = rowgrp * 512 + tid;
        const int r1 = r0 + 256;
        const float i0a = in[r0 * 3], i1a = in[r0 * 3 + 1], i2a = in[r0 * 3 + 2];
        const float i0b = in[r1 * 3], i1b = in[r1 * 3 + 1], i2b = in[r1 * 3 + 2];

        float accA[8], accB[8];
#pragma unroll
        for (int j = 0; j < 8; ++j) { accA[j] = b2[co + j]; accB[j] = accA[j]; }

#pragma unroll 4
        for (int hi = 0; hi < 64; ++hi) {
            const float4 hr = hrow[hi];
            float ha = fmaf(i0a, hr.x, fmaf(i1a, hr.y, fmaf(i2a, hr.z, hr.w)));
            float hb = fmaf(i0b, hr.x, fmaf(i1b, hr.y, fmaf(i2b, hr.z, hr.w)));
            ha = fmaxf(ha, 0.0f);
            hb = fmaxf(hb, 0.0f);
            const float4 wA = w2s[hi * 2], wB = w2s[hi * 2 + 1];
            accA[0] = fmaf(ha, wA.x, accA[0]);  accB[0] = fmaf(hb, wA.x, accB[0]);
            accA[1] = fmaf(ha, wA.y, accA[1]);  accB[1] = fmaf(hb, wA.y, accB[1]);
            accA[2] = fmaf(ha, wA.z, accA[2]);  accB[2] = fmaf(hb, wA.z, accB[2]);
            accA[3] = fmaf(ha, wA.w, accA[3]);  accB[3] = fmaf(hb, wA.w, accB[3]);
            accA[4] = fmaf(ha, wB.x, accA[4]);  accB[4] = fmaf(hb, wB.x, accB[4]);
            accA[5] = fmaf(ha, wB.y, accA[5]);  accB[5] = fmaf(hb, wB.y, accB[5]);
            accA[6] = fmaf(ha, wB.z, accA[6]);  accB[6] = fmaf(hb, wB.z, accB[6]);
            accA[7] = fmaf(ha, wB.w, accA[7]);  accB[7] = fmaf(hb, wB.w, accB[7]);
        }
        float4* o0 = reinterpret_cast<float4*>(out + r0 * 64 + co);
        float4* o1 = reinterpret_cast<float4*>(out + r1 * 64 + co);
        o0[0] = make_float4(accA[0], accA[1], accA[2], accA[3]);
        o0[1] = make_float4(accA[4], accA[5], accA[6], accA[7]);
        o1[0] = make_float4(accB[0], accB[1], accB[2], accB[3]);
        o1[1] = make_float4(accB[4], accB[5], accB[6], accB[7]);
    } else {
        const int sub = bx - 128;       // 0..15
        __shared__ float wall[64 * 8];  // [j]: wv1 x5, bv1, w2o, pad
        __shared__ float b2o_sh;
        if (tid < 64) {
            float s = 0.0f;
            const float4* wv2r = reinterpret_cast<const float4*>(Wv2 + tid * 64);
            const float4* wo4 = reinterpret_cast<const float4*>(Wo);
#pragma unroll 4
            for (int q = 0; q < 16; ++q) {
                const float4 a = wv2r[q], w = wo4[q];
                s = fmaf(a.x, w.x, fmaf(a.y, w.y, fmaf(a.z, w.z, fmaf(a.w, w.w, s))));
            }
            wall[tid * 8 + 0] = Wv1[tid];
            wall[tid * 8 + 1] = Wv1[64 + tid];
            wall[tid * 8 + 2] = Wv1[128 + tid];
            wall[tid * 8 + 3] = Wv1[192 + tid];
            wall[tid * 8 + 4] = Wv1[256 + tid];
            wall[tid * 8 + 5] = bv1[tid];
            wall[tid * 8 + 6] = s;
            wall[tid * 8 + 7] = 0.0f;
        } else if (tid == 64) {
            float s = 0.0f;
            for (int ho = 0; ho < 64; ++ho) s = fmaf(bv2[ho], Wo[ho], s);
            b2o_sh = s;
        }
        __syncthreads();

        const int row = sub * 256 + tid;
        const float* vin = values_f + row * 5;
        const float i0 = vin[0], i1 = vin[1], i2 = vin[2], i3 = vin[3], i4 = vin[4];
        const float4* wall4 = reinterpret_cast<const float4*>(wall);

        float s = b2o_sh;
#pragma unroll 4
        for (int j = 0; j < 64; ++j) {
            const float4 wa = wall4[j * 2], wb = wall4[j * 2 + 1];
            float h = fmaf(i0, wa.x, fmaf(i1, wa.y, fmaf(i2, wa.z,
                      fmaf(i3, wa.w, fmaf(i4, wb.x, wb.y)))));
            h = fmaxf(h, 0.0f);
            s = fmaf(h, wb.z, s);
        }
        vhat[row] = s;
    }
}

// ---------------- Kernel 2: GEMM-tiled L1-dist + in-block softmax partials ----------------
// grid (NT=8, MT=8, BB=4) = 256 blocks (1/CU), 256 threads.
// Block: 128n x 128m. Thread (ty,tx): 8n x 8m register tile.
// LDS 64 KB (K,Q tiles, XOR-swizzled float4 columns).
// Per h4: 16 ds_read_b128 feed 512 VALU -> VALU-bound (LDS pipe at ~66%).
__global__ __launch_bounds__(256)
void fused_kernel(const float* __restrict__ Kb,
                  const float* __restrict__ Qb,
                  const float* __restrict__ vh,
                  float* __restrict__ mxp,
                  float* __restrict__ denp,
                  float* __restrict__ nump) {
    __shared__ float kt[BN * 64];   // 32 KB, swizzled; reused as reduction buffer
    __shared__ float qt[BM * 64];   // 32 KB, swizzled

    const int tid = threadIdx.x;
    const int nt = blockIdx.x, mt = blockIdx.y, b = blockIdx.z;
    const int n0 = nt * BN, m0 = mt * BM;
    const int ty = tid >> 4, tx = tid & 15;

    float4* kt4 = reinterpret_cast<float4*>(kt);
    float4* qt4 = reinterpret_cast<float4*>(qt);

    const float4* ksrc = reinterpret_cast<const float4*>(Kb + (b * NN + n0) * 64);
    const float4* qsrc = reinterpret_cast<const float4*>(Qb + (b * MM + m0) * 64);
#pragma unroll
    for (int l = 0; l < 8; ++l) {
        const int fidx = l * 256 + tid;
        const int row = fidx >> 4, h4 = fidx & 15;
        kt4[row * 16 + (h4 ^ (row & 7))] = ksrc[fidx];
    }
#pragma unroll
    for (int l = 0; l < 8; ++l) {
        const int fidx = l * 256 + tid;
        const int row = fidx >> 4, h4 = fidx & 15;
        qt4[row * 16 + (h4 ^ (row & 7))] = qsrc[fidx];
    }
    __syncthreads();

    const int swk = ty & 7;
    const int swq = tx & 7;

    float acc[8][8];
#pragma unroll
    for (int i = 0; i < 8; ++i)
#pragma unroll
        for (int j = 0; j < 8; ++j) acc[i][j] = 0.0f;

#pragma unroll 2
    for (int h4 = 0; h4 < 16; ++h4) {
        float4 kv[8], qv[8];
#pragma unroll
        for (int ni = 0; ni < 8; ++ni)
            kv[ni] = kt4[(ni * 16 + ty) * 16 + (h4 ^ swk)];
#pragma unroll
        for (int mj = 0; mj < 8; ++mj)
            qv[mj] = qt4[(mj * 16 + tx) * 16 + (h4 ^ swq)];
#pragma unroll
        for (int ni = 0; ni < 8; ++ni)
#pragma unroll
            for (int mj = 0; mj < 8; ++mj) {
                acc[ni][mj] += fabsf(kv[ni].x - qv[mj].x);
                acc[ni][mj] += fabsf(kv[ni].y - qv[mj].y);
                acc[ni][mj] += fabsf(kv[ni].z - qv[mj].z);
                acc[ni][mj] += fabsf(kv[ni].w - qv[mj].w);
            }
    }

    float vloc[8];
#pragma unroll
    for (int ni = 0; ni < 8; ++ni) vloc[ni] = vh[b * NN + n0 + ni * 16 + ty];

    // per-thread two-pass softmax over its 8 n's, for each of its 8 m's
    float mxr[8], denr[8], numr[8];
#pragma unroll
    for (int mj = 0; mj < 8; ++mj) {
        float a[8];
#pragma unroll
        for (int ni = 0; ni < 8; ++ni) {
            const float d = acc[ni][mj];
            a[ni] = d * d * SCALE;
        }
        const float mx = fmaxf(fmaxf(fmaxf(a[0], a[1]), fmaxf(a[2], a[3])),
                               fmaxf(fmaxf(a[4], a[5]), fmaxf(a[6], a[7])));
        float den = 0.0f, num = 0.0f;
#pragma unroll
        for (int ni = 0; ni < 8; ++ni) {
            const float p = __builtin_amdgcn_exp2f(a[ni] - mx);
            den += p;
            num = fmaf(p, vloc[ni], num);
        }
        mxr[mj] = mx; denr[mj] = den; numr[mj] = num;
    }

    // cross-thread (over ty) reduction in LDS: red[ty][mcol][3] (24 KB, aliases kt)
    __syncthreads();
    float* red = kt;
#pragma unroll
    for (int mj = 0; mj < 8; ++mj) {
        const int base = (ty * 128 + mj * 16 + tx) * 3;
        red[base + 0] = mxr[mj];
        red[base + 1] = denr[mj];
        red[base + 2] = numr[mj];
    }
    __syncthreads();

    if (tid < 128) {          // one thread per m-col
        float M = NEG_BIG, D = 0.0f, Nu = 0.0f;
        for (int t = 0; t < 16; ++t) {
            const int base = (t * 128 + tid) * 3;
            const float m2 = red[base + 0];
            const float d2 = red[base + 1];
            const float n2 = red[base + 2];
            const float nm = fmaxf(M, m2);
            const float s0 = __builtin_amdgcn_exp2f(M - nm);
            const float s1 = __builtin_amdgcn_exp2f(m2 - nm);
            D  = D * s0 + d2 * s1;
            Nu = Nu * s0 + n2 * s1;
            M = nm;
        }
        const int p = nt * (BB * MM) + b * MM + m0 + tid;
        mxp[p] = M; denp[p] = D; nump[p] = Nu;
    }
}

// ---------------- Kernel 3: combine n-tile partials ----------------
// grid 64 x 64: thread per (b,m).
__global__ __launch_bounds__(64)
void combine_kernel(const float* __restrict__ mxp,
                    const float* __restrict__ denp,
                    const float* __restrict__ nump,
                    const float* __restrict__ bo,
                    float* __restrict__ out) {
    const int bm = blockIdx.x * 64 + threadIdx.x;   // b*MM + m
    float M = NEG_BIG, D = 0.0f, Nu = 0.0f;
#pragma unroll
    for (int nt = 0; nt < NT; ++nt) {
        const int idx = nt * (BB * MM) + bm;
        const float m2 = mxp[idx];
        const float d2 = denp[idx];
        const float n2 = nump[idx];
        const float nm = fmaxf(M, m2);
        const float s0 = __builtin_amdgcn_exp2f(M - nm);
        const float s1 = __builtin_amdgcn_exp2f(m2 - nm);
        D  = D * s0 + d2 * s1;
        Nu = Nu * s0 + n2 * s1;
        M = nm;
    }
    out[bm] = Nu / D + bo[0];
}

// ---------------- launcher ----------------
extern "C" void kernel_launch(void* const* d_in, const int* in_sizes, int n_in,
                              void* d_out, int out_size, void* d_ws, size_t ws_size,
                              hipStream_t stream) {
    const float* coords_f = (const float*)d_in[0];
    const float* values_f = (const float*)d_in[1];
    const float* coords_t = (const float*)d_in[2];
    const float* Wk1 = (const float*)d_in[3];
    const float* bk1 = (const float*)d_in[4];
    const float* Wk2 = (const float*)d_in[5];
    const float* bk2 = (const float*)d_in[6];
    const float* Wq1 = (const float*)d_in[7];
    const float* bq1 = (const float*)d_in[8];
    const float* Wq2 = (const float*)d_in[9];
    const float* bq2 = (const float*)d_in[10];
    const float* Wv1 = (const float*)d_in[11];
    const float* bv1 = (const float*)d_in[12];
    const float* Wv2 = (const float*)d_in[13];
    const float* bv2 = (const float*)d_in[14];
    const float* Wo  = (const float*)d_in[15];
    const float* bo  = (const float*)d_in[16];

    float* ws  = (float*)d_ws;
    float* Kb  = ws;                      // B*N*H = 262144
    float* Qb  = Kb + BB * NN * HH;       // 262144
    float* vh  = Qb + BB * MM * HH;       // 4096
    float* mxp = vh + BB * NN;            // NT*B*M = 32768
    float* denp = mxp + NT * BB * MM;
    float* nump = denp + NT * BB * MM;

    prep_kernel<<<dim3(144), 256, 0, stream>>>(
        coords_f, values_f, coords_t,
        Wk1, bk1, Wk2, bk2, Wq1, bq1, Wq2, bq2,
        Wv1, bv1, Wv2, bv2, Wo, Kb, Qb, vh);

    fused_kernel<<<dim3(NT, MT, BB), 256, 0, stream>>>(
        Kb, Qb, vh, mxp, denp, nump);

    combine_kernel<<<dim3(64), 64, 0, stream>>>(
        mxp, denp, nump, bo, (float*)d_out);
}